// Round 6
// baseline (137.130 us; speedup 1.0000x reference)
//
#include <hip/hip_runtime.h>

#define N_ENT 400000
#define N_REL 500
#define N_TS 365
#define RANK 64
#define BATCH 256

typedef __attribute__((ext_vector_type(8))) __bf16 bf16x8;
typedef __attribute__((ext_vector_type(16))) float f32x16;
typedef __attribute__((ext_vector_type(4))) float f32x4;

// ---------------------------------------------------------------------------
// Kernel 1: per-batch prep.  256 blocks x 64 threads.
//   V[i][k] = 2*(lhs*rel_ - te*tr)  (bf16), bias[i] = sum_k 2*te*(lhs*tr+te*rel_)
// ---------------------------------------------------------------------------
__global__ void prep_kernel(const float* __restrict__ E0,
                            const float* __restrict__ E1,
                            const float* __restrict__ E2,
                            const float* __restrict__ E3,
                            const float* __restrict__ E4,
                            const int* __restrict__ x,
                            __bf16* __restrict__ Vbf,  // [BATCH][RANK]
                            float* __restrict__ bias)  // [BATCH]
{
    const int i = blockIdx.x;
    const int k = threadIdx.x;

    const int i0 = x[i * 4 + 0];
    const int i1 = x[i * 4 + 1];
    const int i3 = x[i * 4 + 3];

    const float lhs = E0[i0 * RANK + k];
    const float rel = E1[i1 * RANK + k];
    const float te  = E2[i3 * RANK + k];
    const float tr  = E3[i3 * RANK + k];

    // complex_mul(rel, comp_time) with half-width 32
    const int  kh = k & 31;
    const float a = E1[i1 * RANK + kh];
    const float bb = E1[i1 * RANK + 32 + kh];
    const float c = E4[i3 * RANK + kh];
    const float d = E4[i3 * RANK + 32 + kh];
    const float cm = (k < 32) ? (a * c + bb * d) : (a * d - bb * c);
    const float rel_ = rel + cm;

    const float v = 2.0f * (lhs * rel_ - te * tr);
    Vbf[i * RANK + k] = (__bf16)v;

    float rb = 2.0f * te * (lhs * tr + te * rel_);
    #pragma unroll
    for (int off = 32; off > 0; off >>= 1)
        rb += __shfl_down(rb, off, 64);
    if (k == 0) bias[i] = rb;
}

// ---------------------------------------------------------------------------
// Kernel 2: E0 fp32 -> bf16 streaming conversion (A-frag-ready layout = same
// row-major), fused with tail copies + cl_loss.  12500 blocks x 256 threads;
// each thread converts 8 floats (32 B read -> 16 B write, fully coalesced).
// ---------------------------------------------------------------------------
__global__ __launch_bounds__(256) void conv_tail_kernel(
    const float* __restrict__ E0,
    const float* __restrict__ E2,
    const float* __restrict__ E3,
    const float* __restrict__ E4,
    __bf16* __restrict__ Ebf,
    float* __restrict__ out)
{
    const int gid = blockIdx.x * 256 + threadIdx.x;

    // tail outputs (first 91.x blocks)
    const long long SCORES = (long long)BATCH * N_ENT;  // 102,400,000
    const int CP = (N_TS - 1) * RANK;                   // 23,296
    if (gid < CP) {
        out[SCORES + 1 + 0LL * CP + gid] = E2[gid];
        out[SCORES + 1 + 1LL * CP + gid] = E3[gid];
        out[SCORES + 1 + 2LL * CP + gid] = E4[gid];
    }
    if (gid == CP) out[SCORES] = 0.0f;  // cl_loss

    // streaming conversion: 8 floats per thread
    const size_t base = (size_t)gid * 8;  // < 25,600,000
    const f32x4 u0 = *reinterpret_cast<const f32x4*>(E0 + base);
    const f32x4 u1 = *reinterpret_cast<const f32x4*>(E0 + base + 4);
    bf16x8 w;
    w[0] = (__bf16)u0.x;  w[1] = (__bf16)u0.y;
    w[2] = (__bf16)u0.z;  w[3] = (__bf16)u0.w;
    w[4] = (__bf16)u1.x;  w[5] = (__bf16)u1.y;
    w[6] = (__bf16)u1.z;  w[7] = (__bf16)u1.w;
    *reinterpret_cast<bf16x8*>(Ebf + base) = w;
}

// ---------------------------------------------------------------------------
// Kernel 3: scores = V @ E0^T + bias via mfma_f32_32x32x16_bf16.
//   Block = 256 threads = 4 waves; block owns 128 entity columns, wave owns 32.
//   B-frags load directly from bf16 Ebf (L3-hot, written by conv just before).
//   Per 32-row M-tile: MFMA -> LDS transpose (ping-pong, 1 barrier/tile) ->
//   f32x4 row-major stores (each half-wave writes 512 B contiguous).
//   C layout (verified): col=lane&31, row=(reg&3)+8*(reg>>2)+4*(lane>>5).
// ---------------------------------------------------------------------------
__global__ __launch_bounds__(256) void scores_mfma(
    const __bf16* __restrict__ Ebf,
    const __bf16* __restrict__ Vbf,
    const float* __restrict__ bias,
    float* __restrict__ out)
{
    __shared__ float tile[2][32][128];   // 32 KiB ping-pong
    __shared__ float sbias[BATCH];       // 1 KiB

    const int t    = threadIdx.x;
    const int lane = t & 63;
    const int wid  = t >> 6;             // 0..3
    const int l31  = lane & 31;
    const int h    = lane >> 5;          // 0/1
    const int colbase = blockIdx.x * 128;
    const int col  = colbase + wid * 32 + l31;
    const int khalf = h * 8;

    sbias[t] = bias[t];

    // ---- B fragments: 4 x (K=16) over K=64, straight 16 B bf16 loads ----
    bf16x8 bfrag[4];
    const __bf16* erow = Ebf + (size_t)col * RANK + khalf;
    #pragma unroll
    for (int f = 0; f < 4; ++f)
        bfrag[f] = *reinterpret_cast<const bf16x8*>(erow + f * 16);

    int p = 0;
    #pragma unroll 1
    for (int mt = 0; mt < 8; ++mt) {
        const __bf16* arow = Vbf + (size_t)(mt * 32 + l31) * RANK + khalf;

        f32x16 acc;
        #pragma unroll
        for (int j = 0; j < 16; ++j) acc[j] = 0.0f;

        #pragma unroll
        for (int f = 0; f < 4; ++f) {
            const bf16x8 afrag = *reinterpret_cast<const bf16x8*>(arow + f * 16);
            acc = __builtin_amdgcn_mfma_f32_32x32x16_bf16(afrag, bfrag[f], acc, 0, 0, 0);
        }

        // ---- write phase: scatter acc into row-major LDS tile ----
        #pragma unroll
        for (int j = 0; j < 16; ++j) {
            const int row = (j & 3) + 8 * (j >> 2) + 4 * h;
            tile[p][row][wid * 32 + l31] = acc[j];
        }
        __syncthreads();

        // ---- read phase: row-major f32x4 stores, bias folded in ----
        const int m0 = mt * 32;
        #pragma unroll
        for (int q = 0; q < 4; ++q) {
            const int row = q * 8 + (t >> 5);
            f32x4 v = *reinterpret_cast<const f32x4*>(&tile[p][row][(t & 31) * 4]);
            const float bv = sbias[m0 + row];
            v.x += bv; v.y += bv; v.z += bv; v.w += bv;
            *reinterpret_cast<f32x4*>(
                &out[(size_t)(m0 + row) * N_ENT + colbase + (t & 31) * 4]) = v;
        }
        p ^= 1;
        // no second barrier: next iteration writes the other buffer; reuse of
        // this buffer happens only after the NEXT barrier (hazard-checked).
    }
}

// ---------------------------------------------------------------------------
extern "C" void kernel_launch(void* const* d_in, const int* in_sizes, int n_in,
                              void* d_out, int out_size, void* d_ws, size_t ws_size,
                              hipStream_t stream) {
    const float* E0 = (const float*)d_in[0];
    const float* E1 = (const float*)d_in[1];
    const float* E2 = (const float*)d_in[2];
    const float* E3 = (const float*)d_in[3];
    const float* E4 = (const float*)d_in[4];
    const int*   x  = (const int*)d_in[5];

    float* out = (float*)d_out;

    float*  bias = (float*)d_ws;                      // 1 KiB
    __bf16* Vbf  = (__bf16*)((char*)d_ws + 1024);     // 32 KiB
    __bf16* Ebf  = (__bf16*)((char*)d_ws + 65536);    // 51.2 MB

    prep_kernel<<<BATCH, RANK, 0, stream>>>(E0, E1, E2, E3, E4, x, Vbf, bias);

    const int nconv = (N_ENT * RANK / 8) / 256;  // 12500
    conv_tail_kernel<<<nconv, 256, 0, stream>>>(E0, E2, E3, E4, Ebf, out);

    const int nblk = N_ENT / 128;  // 3125
    scores_mfma<<<nblk, 256, 0, stream>>>(Ebf, Vbf, bias, out);
}

// Round 7
// 134.526 us; speedup vs baseline: 1.0194x; 1.0194x over previous
//
#include <hip/hip_runtime.h>

#define N_ENT 400000
#define N_REL 500
#define N_TS 365
#define RANK 64
#define BATCH 256

typedef __attribute__((ext_vector_type(8))) __bf16 bf16x8;
typedef __attribute__((ext_vector_type(16))) float f32x16;
typedef __attribute__((ext_vector_type(4))) float f32x4;

// ---------------------------------------------------------------------------
// Kernel 1: fused prep + tail.  Grid = 365 blocks x 64 threads.
//   blocks 0..255 : batch prep -> Vbf (bf16) + bias
//   blocks 0..363 : copy row b of E2/E3/E4 into the tail outputs
//   block 364     : cl_loss = 0
// ---------------------------------------------------------------------------
__global__ void prep_tail_kernel(const float* __restrict__ E0,
                                 const float* __restrict__ E1,
                                 const float* __restrict__ E2,
                                 const float* __restrict__ E3,
                                 const float* __restrict__ E4,
                                 const int* __restrict__ x,
                                 __bf16* __restrict__ Vbf,  // [BATCH][RANK]
                                 float* __restrict__ bias,  // [BATCH]
                                 float* __restrict__ out)
{
    const int b = blockIdx.x;
    const int k = threadIdx.x;

    const long long SCORES = (long long)BATCH * N_ENT;  // 102,400,000
    const int CP = (N_TS - 1) * RANK;                   // 23,296

    if (b == 364 && k == 0) out[SCORES] = 0.0f;  // cl_loss
    if (b < N_TS - 1) {
        const int idx = b * RANK + k;
        out[SCORES + 1 + 0LL * CP + idx] = E2[idx];
        out[SCORES + 1 + 1LL * CP + idx] = E3[idx];
        out[SCORES + 1 + 2LL * CP + idx] = E4[idx];
    }

    if (b < BATCH) {
        const int i = b;
        const int i0 = x[i * 4 + 0];
        const int i1 = x[i * 4 + 1];
        const int i3 = x[i * 4 + 3];

        const float lhs = E0[i0 * RANK + k];
        const float rel = E1[i1 * RANK + k];
        const float te  = E2[i3 * RANK + k];
        const float tr  = E3[i3 * RANK + k];

        // complex_mul(rel, comp_time) with half-width 32
        const int  kh = k & 31;
        const float a = E1[i1 * RANK + kh];
        const float bb = E1[i1 * RANK + 32 + kh];
        const float c = E4[i3 * RANK + kh];
        const float d = E4[i3 * RANK + 32 + kh];
        const float cm = (k < 32) ? (a * c + bb * d) : (a * d - bb * c);
        const float rel_ = rel + cm;

        const float v = 2.0f * (lhs * rel_ - te * tr);
        Vbf[i * RANK + k] = (__bf16)v;

        float rb = 2.0f * te * (lhs * tr + te * rel_);
        #pragma unroll
        for (int off = 32; off > 0; off >>= 1)
            rb += __shfl_down(rb, off, 64);
        if (k == 0) bias[i] = rb;
    }
}

// ---------------------------------------------------------------------------
// Kernel 2: scores = V @ E0^T + bias via mfma_f32_32x32x16_bf16.
//   Block = 256 threads = 4 waves; block owns 128 entity columns, wave owns 32.
//   ZERO-BARRIER output transpose: each wave transposes its own 32x32 tile in
//   its own LDS region (same-wave ds_write->ds_read needs only lgkmcnt, which
//   the compiler emits) -> global stores are never drained by barriers and
//   stream freely across tiles.  Bias is copied to LDS by every wave
//   (benign identical-value race; wave-local lgkm ordering makes each wave's
//   reads correct).  A-frags prefetched one tile ahead, issued BEFORE the
//   stores, so their vmcnt wait is counted and leaves stores in flight.
//   LDS tile row stride 36 dwords: rows 16B-aligned (f32x4 legal); write
//   banks (4r+c)%32 distinct per half-wave; readback uniform 8 dwords/bank.
//   C layout (verified): col=lane&31, row=(reg&3)+8*(reg>>2)+4*(lane>>5).
// ---------------------------------------------------------------------------
__global__ __launch_bounds__(256) void scores_mfma(
    const float* __restrict__ E0,
    const __bf16* __restrict__ Vbf,
    const float* __restrict__ bias,
    float* __restrict__ out)
{
    __shared__ __align__(16) float lt[4][32][36];  // per-wave tiles, 18 KiB
    __shared__ float sb[BATCH];                    // 1 KiB

    const int t    = threadIdx.x;
    const int lane = t & 63;
    const int wid  = t >> 6;             // 0..3
    const int l31  = lane & 31;
    const int h    = lane >> 5;          // 0/1
    const int colbase = blockIdx.x * 128;
    const int wcol = colbase + wid * 32;           // wave's column base
    const int col  = wcol + l31;
    const int khalf = h * 8;

    // benign-duplicate bias copy (all waves write identical values)
    #pragma unroll
    for (int r = 0; r < 4; ++r)
        sb[r * 64 + lane] = bias[r * 64 + lane];

    // ---- B fragments: 4 x (K=16) over K=64, fp32 -> bf16 in-register ----
    bf16x8 bfrag[4];
    const float* erow = E0 + (size_t)col * RANK;
    #pragma unroll
    for (int f = 0; f < 4; ++f) {
        const int kb = f * 16 + khalf;
        const float4 u0 = *reinterpret_cast<const float4*>(erow + kb);
        const float4 u1 = *reinterpret_cast<const float4*>(erow + kb + 4);
        bfrag[f][0] = (__bf16)u0.x;  bfrag[f][1] = (__bf16)u0.y;
        bfrag[f][2] = (__bf16)u0.z;  bfrag[f][3] = (__bf16)u0.w;
        bfrag[f][4] = (__bf16)u1.x;  bfrag[f][5] = (__bf16)u1.y;
        bfrag[f][6] = (__bf16)u1.z;  bfrag[f][7] = (__bf16)u1.w;
    }

    float (*tile)[36] = lt[wid];
    const int rrow = lane >> 3;          // 0..7
    const int rcol = (lane & 7) * 4;     // 0,4,...,28

    const __bf16* abase = Vbf + (size_t)l31 * RANK + khalf;

    // preload A-frags for mt=0
    bf16x8 a0 = *reinterpret_cast<const bf16x8*>(abase);
    bf16x8 a1 = *reinterpret_cast<const bf16x8*>(abase + 16);
    bf16x8 a2 = *reinterpret_cast<const bf16x8*>(abase + 32);
    bf16x8 a3 = *reinterpret_cast<const bf16x8*>(abase + 48);

    #pragma unroll 1
    for (int mt = 0; mt < 8; ++mt) {
        f32x16 acc;
        #pragma unroll
        for (int j = 0; j < 16; ++j) acc[j] = 0.0f;
        acc = __builtin_amdgcn_mfma_f32_32x32x16_bf16(a0, bfrag[0], acc, 0, 0, 0);
        acc = __builtin_amdgcn_mfma_f32_32x32x16_bf16(a1, bfrag[1], acc, 0, 0, 0);
        acc = __builtin_amdgcn_mfma_f32_32x32x16_bf16(a2, bfrag[2], acc, 0, 0, 0);
        acc = __builtin_amdgcn_mfma_f32_32x32x16_bf16(a3, bfrag[3], acc, 0, 0, 0);

        // prefetch next tile's A-frags (issued before this tile's stores ->
        // their vmcnt wait is counted, stores stay outstanding)
        const __bf16* anext = abase + (size_t)(((mt + 1) & 7) * 32) * RANK;
        const bf16x8 n0 = *reinterpret_cast<const bf16x8*>(anext);
        const bf16x8 n1 = *reinterpret_cast<const bf16x8*>(anext + 16);
        const bf16x8 n2 = *reinterpret_cast<const bf16x8*>(anext + 32);
        const bf16x8 n3 = *reinterpret_cast<const bf16x8*>(anext + 48);

        // ---- scatter acc into this wave's LDS tile ----
        #pragma unroll
        for (int j = 0; j < 16; ++j) {
            const int row = (j & 3) + 8 * (j >> 2) + 4 * h;
            tile[row][l31] = acc[j];
        }

        // ---- wave-local readback + f32x4 stores (no barrier anywhere) ----
        const int m0 = mt * 32;
        #pragma unroll
        for (int q = 0; q < 4; ++q) {
            const int row = q * 8 + rrow;
            const int m = m0 + row;
            f32x4 v = *reinterpret_cast<const f32x4*>(&tile[row][rcol]);
            const float bv = sb[m];
            v.x += bv; v.y += bv; v.z += bv; v.w += bv;
            *reinterpret_cast<f32x4*>(&out[(size_t)m * N_ENT + wcol + rcol]) = v;
        }

        a0 = n0; a1 = n1; a2 = n2; a3 = n3;
    }
}

// ---------------------------------------------------------------------------
extern "C" void kernel_launch(void* const* d_in, const int* in_sizes, int n_in,
                              void* d_out, int out_size, void* d_ws, size_t ws_size,
                              hipStream_t stream) {
    const float* E0 = (const float*)d_in[0];
    const float* E1 = (const float*)d_in[1];
    const float* E2 = (const float*)d_in[2];
    const float* E3 = (const float*)d_in[3];
    const float* E4 = (const float*)d_in[4];
    const int*   x  = (const int*)d_in[5];

    float* out = (float*)d_out;

    float*  bias = (float*)d_ws;                    // 1 KiB
    __bf16* Vbf  = (__bf16*)((char*)d_ws + 1024);   // 32 KiB

    prep_tail_kernel<<<N_TS, RANK, 0, stream>>>(E0, E1, E2, E3, E4, x, Vbf, bias, out);

    const int nblk = N_ENT / 128;  // 3125
    scores_mfma<<<nblk, 256, 0, stream>>>(E0, Vbf, bias, out);
}

// Round 8
// 120.833 us; speedup vs baseline: 1.1349x; 1.1133x over previous
//
#include <hip/hip_runtime.h>

#define N_ENT 400000
#define N_REL 500
#define N_TS 365
#define RANK 64
#define BATCH 256

typedef __attribute__((ext_vector_type(8))) __bf16 bf16x8;
typedef __attribute__((ext_vector_type(16))) float f32x16;
typedef __attribute__((ext_vector_type(4))) float f32x4;

// ---------------------------------------------------------------------------
// Kernel 1: fused prep + tail.  Grid = 365 blocks x 64 threads.
// ---------------------------------------------------------------------------
__global__ void prep_tail_kernel(const float* __restrict__ E0,
                                 const float* __restrict__ E1,
                                 const float* __restrict__ E2,
                                 const float* __restrict__ E3,
                                 const float* __restrict__ E4,
                                 const int* __restrict__ x,
                                 __bf16* __restrict__ Vbf,  // [BATCH][RANK]
                                 float* __restrict__ bias,  // [BATCH]
                                 float* __restrict__ out)
{
    const int b = blockIdx.x;
    const int k = threadIdx.x;

    const long long SCORES = (long long)BATCH * N_ENT;  // 102,400,000
    const int CP = (N_TS - 1) * RANK;                   // 23,296

    if (b == 364 && k == 0) out[SCORES] = 0.0f;  // cl_loss
    if (b < N_TS - 1) {
        const int idx = b * RANK + k;
        out[SCORES + 1 + 0LL * CP + idx] = E2[idx];
        out[SCORES + 1 + 1LL * CP + idx] = E3[idx];
        out[SCORES + 1 + 2LL * CP + idx] = E4[idx];
    }

    if (b < BATCH) {
        const int i = b;
        const int i0 = x[i * 4 + 0];
        const int i1 = x[i * 4 + 1];
        const int i3 = x[i * 4 + 3];

        const float lhs = E0[i0 * RANK + k];
        const float rel = E1[i1 * RANK + k];
        const float te  = E2[i3 * RANK + k];
        const float tr  = E3[i3 * RANK + k];

        // complex_mul(rel, comp_time) with half-width 32
        const int  kh = k & 31;
        const float a = E1[i1 * RANK + kh];
        const float bb = E1[i1 * RANK + 32 + kh];
        const float c = E4[i3 * RANK + kh];
        const float d = E4[i3 * RANK + 32 + kh];
        const float cm = (k < 32) ? (a * c + bb * d) : (a * d - bb * c);
        const float rel_ = rel + cm;

        const float v = 2.0f * (lhs * rel_ - te * tr);
        Vbf[i * RANK + k] = (__bf16)v;

        float rb = 2.0f * te * (lhs * tr + te * rel_);
        #pragma unroll
        for (int off = 32; off > 0; off >>= 1)
            rb += __shfl_down(rb, off, 64);
        if (k == 0) bias[i] = rb;
    }
}

// ---------------------------------------------------------------------------
// Kernel 2: scores = V @ E0^T + bias via mfma_f32_32x32x16_bf16.
//   Block = 256 threads = 4 waves; block owns 256 entity columns (2 column-
//   tiles per wave).  Per 32-row M-tile: 8 MFMAs -> LDS 32x256 transpose
//   (2 barriers) -> readback where EACH WAVE writes ONE FULL ROW SEGMENT of
//   1 KB contiguous (64 lanes x 16 B).  XCD-bijective block swizzle gives
//   each XCD a contiguous column range (write locality in its private L2).
//   Tail block (last of 1563) covers only 128 cols: ctile 1 skipped
//   (wave-uniform), stores lane-guarded.
//   C layout (verified): col=lane&31, row=(reg&3)+8*(reg>>2)+4*(lane>>5).
// ---------------------------------------------------------------------------
__global__ __launch_bounds__(256) void scores_mfma(
    const float* __restrict__ E0,
    const __bf16* __restrict__ Vbf,
    const float* __restrict__ bias,
    float* __restrict__ out)
{
    __shared__ __align__(16) float tile[32][256];  // 32 KiB
    __shared__ float sb[BATCH];                    // 1 KiB

    const int t    = threadIdx.x;
    const int lane = t & 63;
    const int wid  = t >> 6;             // 0..3
    const int l31  = lane & 31;
    const int h    = lane >> 5;          // 0/1
    const int khalf = h * 8;

    // ---- XCD-bijective swizzle (nwg = 1563 = 8*195 + 3) ----
    const int nwg = gridDim.x;
    const int qq  = nwg >> 3;            // 195
    const int rr  = nwg & 7;             // 3
    const int xcd = blockIdx.x & 7;
    const int idx = blockIdx.x >> 3;
    const int swz = (xcd < rr ? xcd * (qq + 1) : rr * (qq + 1) + (xcd - rr) * qq) + idx;

    const int colbase = swz * 256;
    const bool has_c1 = (colbase + 128) < N_ENT;   // false only for tail block

    sb[t] = bias[t];

    // ---- B fragments: 2 ctiles x 4 x (K=16), fp32 -> bf16 in-register ----
    bf16x8 bfrag[2][4];
    #pragma unroll
    for (int c = 0; c < 2; ++c) {
        if (c == 1 && !has_c1) break;
        const float* erow = E0 + (size_t)(colbase + c * 128 + wid * 32 + l31) * RANK;
        #pragma unroll
        for (int f = 0; f < 4; ++f) {
            const int kb = f * 16 + khalf;
            const float4 u0 = *reinterpret_cast<const float4*>(erow + kb);
            const float4 u1 = *reinterpret_cast<const float4*>(erow + kb + 4);
            bfrag[c][f][0] = (__bf16)u0.x;  bfrag[c][f][1] = (__bf16)u0.y;
            bfrag[c][f][2] = (__bf16)u0.z;  bfrag[c][f][3] = (__bf16)u0.w;
            bfrag[c][f][4] = (__bf16)u1.x;  bfrag[c][f][5] = (__bf16)u1.y;
            bfrag[c][f][6] = (__bf16)u1.z;  bfrag[c][f][7] = (__bf16)u1.w;
        }
    }

    #pragma unroll 1
    for (int mt = 0; mt < 8; ++mt) {
        const __bf16* arow = Vbf + (size_t)(mt * 32 + l31) * RANK + khalf;
        bf16x8 afrag[4];
        #pragma unroll
        for (int f = 0; f < 4; ++f)
            afrag[f] = *reinterpret_cast<const bf16x8*>(arow + f * 16);

        #pragma unroll
        for (int c = 0; c < 2; ++c) {
            if (c == 1 && !has_c1) break;
            f32x16 acc;
            #pragma unroll
            for (int j = 0; j < 16; ++j) acc[j] = 0.0f;
            #pragma unroll
            for (int f = 0; f < 4; ++f)
                acc = __builtin_amdgcn_mfma_f32_32x32x16_bf16(afrag[f], bfrag[c][f], acc, 0, 0, 0);

            // scatter into LDS (bank = l31, conflict-free)
            #pragma unroll
            for (int j = 0; j < 16; ++j) {
                const int row = (j & 3) + 8 * (j >> 2) + 4 * h;
                tile[row][c * 128 + wid * 32 + l31] = acc[j];
            }
        }
        __syncthreads();

        // ---- readback: wave w writes row q*4+w, 1 KB contiguous ----
        const int m0 = mt * 32;
        const int cd = lane * 4;             // col dword within 256
        const bool sok = (colbase + cd) < N_ENT;
        #pragma unroll
        for (int qp = 0; qp < 8; ++qp) {
            const int row = qp * 4 + wid;
            const int m = m0 + row;
            f32x4 v = *reinterpret_cast<const f32x4*>(&tile[row][cd]);
            const float bv = sb[m];
            v.x += bv; v.y += bv; v.z += bv; v.w += bv;
            if (sok)
                *reinterpret_cast<f32x4*>(&out[(size_t)m * N_ENT + colbase + cd]) = v;
        }
        __syncthreads();
    }
}

// ---------------------------------------------------------------------------
extern "C" void kernel_launch(void* const* d_in, const int* in_sizes, int n_in,
                              void* d_out, int out_size, void* d_ws, size_t ws_size,
                              hipStream_t stream) {
    const float* E0 = (const float*)d_in[0];
    const float* E1 = (const float*)d_in[1];
    const float* E2 = (const float*)d_in[2];
    const float* E3 = (const float*)d_in[3];
    const float* E4 = (const float*)d_in[4];
    const int*   x  = (const int*)d_in[5];

    float* out = (float*)d_out;

    float*  bias = (float*)d_ws;                    // 1 KiB
    __bf16* Vbf  = (__bf16*)((char*)d_ws + 1024);   // 32 KiB

    prep_tail_kernel<<<N_TS, RANK, 0, stream>>>(E0, E1, E2, E3, E4, x, Vbf, bias, out);

    const int nblk = (N_ENT + 255) / 256;  // 1563 (last block: 128 cols)
    scores_mfma<<<nblk, 256, 0, stream>>>(E0, Vbf, bias, out);
}